// Round 2
// baseline (344.362 us; speedup 1.0000x reference)
//
#include <hip/hip_runtime.h>

typedef short bf16x8 __attribute__((ext_vector_type(8)));
typedef float f32x4 __attribute__((ext_vector_type(4)));
typedef unsigned short u16;
typedef unsigned int u32;

#define N_TOK 2048
#define D_EMB 1024
#define D_FFNC 2048
#define N_EXP 8

__device__ __forceinline__ u16 f2bf(float f) {
    u32 u = __builtin_bit_cast(u32, f);
    u32 r = (u + 0x7fffu + ((u >> 16) & 1u)) >> 16;
    return (u16)r;
}

__device__ __forceinline__ void gl_lds16(const void* g, void* l) {
    __builtin_amdgcn_global_load_lds((const __attribute__((address_space(1))) u32*)g,
                                     (__attribute__((address_space(3))) u32*)l, 16, 0, 0);
}

// ---------------- router: fp32 logits, softmax, top-2, renorm; x -> bf16 ----
__global__ __launch_bounds__(256) void k_router(const float* __restrict__ x,
                                                const float* __restrict__ wr,
                                                u16* __restrict__ xb,
                                                int* __restrict__ eids,
                                                float* __restrict__ gate2) {
    int lane = threadIdx.x & 63;
    int wv = threadIdx.x >> 6;
    int t = blockIdx.x * 4 + wv;
    const float* xp = x + (size_t)t * D_EMB;
    float p[N_EXP];
#pragma unroll
    for (int e = 0; e < N_EXP; e++) p[e] = 0.f;
#pragma unroll
    for (int i = 0; i < 4; i++) {
        int idx = (i * 64 + lane) * 4;
        float4 v = *reinterpret_cast<const float4*>(xp + idx);
        ushort4 o;
        o.x = f2bf(v.x); o.y = f2bf(v.y); o.z = f2bf(v.z); o.w = f2bf(v.w);
        *reinterpret_cast<ushort4*>(xb + (size_t)t * D_EMB + idx) = o;
#pragma unroll
        for (int e = 0; e < N_EXP; e++) {
            float4 w = *reinterpret_cast<const float4*>(wr + e * D_EMB + idx);
            p[e] += v.x * w.x + v.y * w.y + v.z * w.z + v.w * w.w;
        }
    }
#pragma unroll
    for (int off = 32; off; off >>= 1) {
#pragma unroll
        for (int e = 0; e < N_EXP; e++) p[e] += __shfl_xor(p[e], off);
    }
    float mx = p[0];
#pragma unroll
    for (int e = 1; e < N_EXP; e++) mx = fmaxf(mx, p[e]);
    float pr[N_EXP];
#pragma unroll
    for (int e = 0; e < N_EXP; e++) pr[e] = expf(p[e] - mx);
    int e1 = 0; float v1 = pr[0];
#pragma unroll
    for (int e = 1; e < N_EXP; e++) { if (pr[e] > v1) { v1 = pr[e]; e1 = e; } }
    int e2 = -1; float v2 = -1.f;
#pragma unroll
    for (int e = 0; e < N_EXP; e++) { if (e != e1 && pr[e] > v2) { v2 = pr[e]; e2 = e; } }
    if (lane == 0) {
        float inv = 1.f / (v1 + v2);
        eids[t * 2] = e1; eids[t * 2 + 1] = e2;
        gate2[t * 2] = v1 * inv; gate2[t * 2 + 1] = v2 * inv;
    }
}

// ---------------- transpose+convert: fp32 [R][C] -> bf16 [C][R] -------------
__global__ __launch_bounds__(256) void k_transpose(const float* __restrict__ in,
                                                   u16* __restrict__ out, int R, int C) {
    __shared__ float tl[64][65];
    int c0 = blockIdx.x * 64, r0 = blockIdx.y * 64;
    int tid = threadIdx.x;
    int rr = tid >> 4, c4 = (tid & 15) * 4;
#pragma unroll
    for (int i = 0; i < 4; i++) {
        int r = rr + i * 16;
        float4 v = *reinterpret_cast<const float4*>(in + (size_t)(r0 + r) * C + c0 + c4);
        tl[r][c4] = v.x; tl[r][c4 + 1] = v.y; tl[r][c4 + 2] = v.z; tl[r][c4 + 3] = v.w;
    }
    __syncthreads();
    int k4 = (tid & 15) * 4;
#pragma unroll
    for (int i = 0; i < 4; i++) {
        int cc = rr + i * 16;
        ushort4 o;
        o.x = f2bf(tl[k4][cc]); o.y = f2bf(tl[k4 + 1][cc]);
        o.z = f2bf(tl[k4 + 2][cc]); o.w = f2bf(tl[k4 + 3][cc]);
        *reinterpret_cast<ushort4*>(out + (size_t)(c0 + cc) * R + r0 + k4) = o;
    }
}

// ---------------- build per-expert row lists --------------------------------
__global__ __launch_bounds__(256) void k_build(const int* __restrict__ eids,
                                               const float* __restrict__ gate2,
                                               int* __restrict__ cnt, int* __restrict__ basep,
                                               int* __restrict__ rowmeta, float* __restrict__ rowgate) {
    __shared__ int scnt[8], sbase[8], sfill[8];
    int tid = threadIdx.x;
    if (tid < 8) { scnt[tid] = 0; sfill[tid] = 0; }
    __syncthreads();
    for (int t = tid; t < N_TOK; t += 256) {
        atomicAdd(&scnt[eids[2 * t]], 1);
        atomicAdd(&scnt[eids[2 * t + 1]], 1);
    }
    __syncthreads();
    if (tid == 0) { int s = 0; for (int e = 0; e < 8; e++) { sbase[e] = s; s += scnt[e]; } }
    __syncthreads();
    if (tid < 8) { cnt[tid] = scnt[tid]; basep[tid] = sbase[tid]; }
    for (int t = tid; t < N_TOK; t += 256) {
#pragma unroll
        for (int s = 0; s < 2; s++) {
            int e = eids[2 * t + s];
            int pos = atomicAdd(&sfill[e], 1);
            int g = sbase[e] + pos;
            rowmeta[g] = t | (s << 16);
            rowgate[g] = gate2[2 * t + s];
        }
    }
}

// ---------------- GEMM1: h = gelu(x_gathered @ w1_e), bf16 out --------------
// LDS tiles 128x64 bf16; LDS[r][chunk c] = global[r][c ^ (r&7)] (16B chunks).
// global_load_lds: dst base is WAVE-UNIFORM; HW adds lane*16B. Lane l covers
// row (base + l>>3), chunk (l&7); source pre-swizzled so read-side XOR undoes.
__global__ __launch_bounds__(256) void k_gemm1(const u16* __restrict__ xb,
                                               const u16* __restrict__ w1t,
                                               const int* __restrict__ cnt,
                                               const int* __restrict__ basep,
                                               const int* __restrict__ rowmeta,
                                               u16* __restrict__ hbuf) {
    int e = blockIdx.z;
    int nrows = cnt[e];
    int mt = blockIdx.x, nt = blockIdx.y;
    if (mt * 128 >= nrows) return;
    int b0 = basep[e];
    __shared__ u16 lA[128 * 64];
    __shared__ u16 lB[128 * 64];
    int tid = threadIdx.x, lane = tid & 63, wv = tid >> 6;
    int srow8 = lane >> 3;
    int c8 = lane & 7;
    int csw = (c8 ^ srow8) * 16;  // pre-swizzled source chunk (bytes)
    const char* xbB = (const char*)xb;
    const char* w1tB = (const char*)w1t;
    size_t asrc[4], bsrc[4];
    u16 *adst[4], *bdst[4];
#pragma unroll
    for (int i = 0; i < 4; i++) {
        int r = wv * 32 + i * 8 + srow8;
        int g = mt * 128 + r;
        int tok = (g < nrows) ? (rowmeta[b0 + g] & 0xffff) : (rowmeta[b0] & 0xffff);
        asrc[i] = (size_t)tok * 2048 + csw;
        int colg = nt * 128 + r;
        bsrc[i] = (size_t)(e * 2048 + colg) * 2048 + csw;
        adst[i] = lA + (wv * 32 + i * 8) * 64;  // wave-uniform base
        bdst[i] = lB + (wv * 32 + i * 8) * 64;
    }
    f32x4 acc[4][4];
#pragma unroll
    for (int m = 0; m < 4; m++)
#pragma unroll
        for (int n = 0; n < 4; n++) acc[m][n] = (f32x4){0.f, 0.f, 0.f, 0.f};
    int wr = (wv >> 1) * 64, wc = (wv & 1) * 64;
    int lr = lane & 15, kg = lane >> 4;
#pragma unroll
    for (int i = 0; i < 4; i++) { gl_lds16(xbB + asrc[i], adst[i]); gl_lds16(w1tB + bsrc[i], bdst[i]); }
    for (int kt = 0; kt < 16; kt++) {
        __syncthreads();
#pragma unroll
        for (int h2 = 0; h2 < 2; h2++) {
            bf16x8 af[4], bfr[4];
#pragma unroll
            for (int m = 0; m < 4; m++)
                af[m] = *(const bf16x8*)(lA + (wr + m * 16 + lr) * 64 + (((h2 * 4 + kg) ^ (lr & 7)) * 8));
#pragma unroll
            for (int n = 0; n < 4; n++)
                bfr[n] = *(const bf16x8*)(lB + (wc + n * 16 + lr) * 64 + (((h2 * 4 + kg) ^ (lr & 7)) * 8));
#pragma unroll
            for (int m = 0; m < 4; m++)
#pragma unroll
                for (int n = 0; n < 4; n++)
                    acc[m][n] = __builtin_amdgcn_mfma_f32_16x16x32_bf16(af[m], bfr[n], acc[m][n], 0, 0, 0);
        }
        __syncthreads();
        if (kt < 15) {
            size_t ko = (size_t)(kt + 1) * 128;
#pragma unroll
            for (int i = 0; i < 4; i++) { gl_lds16(xbB + asrc[i] + ko, adst[i]); gl_lds16(w1tB + bsrc[i] + ko, bdst[i]); }
        }
    }
#pragma unroll
    for (int m = 0; m < 4; m++) {
        int rbase = wr + m * 16 + kg * 4;
#pragma unroll
        for (int j = 0; j < 4; j++) {
            int r = mt * 128 + rbase + j;
            if (r < nrows) {
                u16* hp = hbuf + (size_t)(b0 + r) * D_FFNC + nt * 128 + wc + lr;
#pragma unroll
                for (int n = 0; n < 4; n++) {
                    float v = acc[m][n][j];
                    v = 0.5f * v * (1.f + erff(v * 0.70710678118654752f));
                    hp[n * 16] = f2bf(v);
                }
            }
        }
    }
}

// ---------------- GEMM2: out2[tok][slot] = gate * (h @ w2_e) ----------------
__global__ __launch_bounds__(256) void k_gemm2(const u16* __restrict__ hbuf,
                                               const u16* __restrict__ w2t,
                                               const int* __restrict__ cnt,
                                               const int* __restrict__ basep,
                                               const int* __restrict__ rowmeta,
                                               const float* __restrict__ rowgate,
                                               float* __restrict__ out2) {
    int e = blockIdx.z;
    int nrows = cnt[e];
    int mt = blockIdx.x, nt = blockIdx.y;  // nt 0..7
    if (mt * 128 >= nrows) return;
    int b0 = basep[e];
    __shared__ u16 lA[128 * 64];
    __shared__ u16 lB[128 * 64];
    int tid = threadIdx.x, lane = tid & 63, wv = tid >> 6;
    int srow8 = lane >> 3;
    int c8 = lane & 7;
    int csw = (c8 ^ srow8) * 16;
    const char* hB = (const char*)hbuf;
    const char* w2tB = (const char*)w2t;
    size_t asrc[4], bsrc[4];
    u16 *adst[4], *bdst[4];
#pragma unroll
    for (int i = 0; i < 4; i++) {
        int r = wv * 32 + i * 8 + srow8;
        int g = mt * 128 + r;
        int hr = b0 + ((g < nrows) ? g : (nrows - 1));
        asrc[i] = (size_t)hr * 4096 + csw;
        int colg = nt * 128 + r;  // 0..1023
        bsrc[i] = (size_t)colg * 32768 + (size_t)e * 4096 + csw;
        adst[i] = lA + (wv * 32 + i * 8) * 64;  // wave-uniform base
        bdst[i] = lB + (wv * 32 + i * 8) * 64;
    }
    f32x4 acc[4][4];
#pragma unroll
    for (int m = 0; m < 4; m++)
#pragma unroll
        for (int n = 0; n < 4; n++) acc[m][n] = (f32x4){0.f, 0.f, 0.f, 0.f};
    int wr = (wv >> 1) * 64, wc = (wv & 1) * 64;
    int lr = lane & 15, kg = lane >> 4;
#pragma unroll
    for (int i = 0; i < 4; i++) { gl_lds16(hB + asrc[i], adst[i]); gl_lds16(w2tB + bsrc[i], bdst[i]); }
    for (int kt = 0; kt < 32; kt++) {
        __syncthreads();
#pragma unroll
        for (int h2 = 0; h2 < 2; h2++) {
            bf16x8 af[4], bfr[4];
#pragma unroll
            for (int m = 0; m < 4; m++)
                af[m] = *(const bf16x8*)(lA + (wr + m * 16 + lr) * 64 + (((h2 * 4 + kg) ^ (lr & 7)) * 8));
#pragma unroll
            for (int n = 0; n < 4; n++)
                bfr[n] = *(const bf16x8*)(lB + (wc + n * 16 + lr) * 64 + (((h2 * 4 + kg) ^ (lr & 7)) * 8));
#pragma unroll
            for (int m = 0; m < 4; m++)
#pragma unroll
                for (int n = 0; n < 4; n++)
                    acc[m][n] = __builtin_amdgcn_mfma_f32_16x16x32_bf16(af[m], bfr[n], acc[m][n], 0, 0, 0);
        }
        __syncthreads();
        if (kt < 31) {
            size_t ko = (size_t)(kt + 1) * 128;
#pragma unroll
            for (int i = 0; i < 4; i++) { gl_lds16(hB + asrc[i] + ko, adst[i]); gl_lds16(w2tB + bsrc[i] + ko, bdst[i]); }
        }
    }
#pragma unroll
    for (int m = 0; m < 4; m++) {
        int rbase = wr + m * 16 + kg * 4;
#pragma unroll
        for (int j = 0; j < 4; j++) {
            int r = mt * 128 + rbase + j;
            if (r < nrows) {
                int meta = rowmeta[b0 + r];
                int tok = meta & 0xffff;
                int slot = meta >> 16;
                float gw = rowgate[b0 + r];
                float* op = out2 + ((size_t)tok * 2 + slot) * D_EMB + nt * 128 + wc + lr;
#pragma unroll
                for (int n = 0; n < 4; n++) op[n * 16] = gw * acc[m][n][j];
            }
        }
    }
}

// ---------------- combine the two expert slots ------------------------------
__global__ __launch_bounds__(256) void k_combine(const float* __restrict__ out2,
                                                 float* __restrict__ out) {
    int idx = blockIdx.x * 256 + threadIdx.x;  // float4 id, total 524288
    int t = idx >> 8;
    int d4 = (idx & 255) * 4;
    float4 a = *reinterpret_cast<const float4*>(out2 + (size_t)t * 2 * D_EMB + d4);
    float4 b = *reinterpret_cast<const float4*>(out2 + ((size_t)t * 2 + 1) * D_EMB + d4);
    float4 r;
    r.x = a.x + b.x; r.y = a.y + b.y; r.z = a.z + b.z; r.w = a.w + b.w;
    *reinterpret_cast<float4*>(out + (size_t)t * D_EMB + d4) = r;
}

extern "C" void kernel_launch(void* const* d_in, const int* in_sizes, int n_in,
                              void* d_out, int out_size, void* d_ws, size_t ws_size,
                              hipStream_t stream) {
    const float* x = (const float*)d_in[0];
    const float* wrt = (const float*)d_in[1];
    const float* w1 = (const float*)d_in[2];
    const float* w2 = (const float*)d_in[3];
    float* out = (float*)d_out;
    char* ws = (char*)d_ws;
    size_t off = 0;
    auto alloc = [&](size_t b) { void* p = ws + off; off += (b + 255) & ~(size_t)255; return p; };
    u16* xb = (u16*)alloc((size_t)N_TOK * D_EMB * 2);
    u16* w1t = (u16*)alloc((size_t)16384 * 1024 * 2);
    u16* w2t = (u16*)alloc((size_t)16384 * 1024 * 2);
    u16* hbuf = (u16*)alloc((size_t)4096 * D_FFNC * 2);
    float* out2 = (float*)alloc((size_t)N_TOK * 2 * D_EMB * 4);
    int* eids = (int*)alloc(N_TOK * 2 * 4);
    float* gate2 = (float*)alloc(N_TOK * 2 * 4);
    int* rowmeta = (int*)alloc(4096 * 4);
    float* rowgate = (float*)alloc(4096 * 4);
    int* cnt = (int*)alloc(64);
    int* basep = (int*)alloc(64);

    k_router<<<512, 256, 0, stream>>>(x, wrt, xb, eids, gate2);
    k_transpose<<<dim3(256, 16), 256, 0, stream>>>(w1, w1t, 1024, 16384);
    k_transpose<<<dim3(16, 256), 256, 0, stream>>>(w2, w2t, 16384, 1024);
    k_build<<<1, 256, 0, stream>>>(eids, gate2, cnt, basep, rowmeta, rowgate);
    k_gemm1<<<dim3(16, 16, 8), 256, 0, stream>>>(xb, w1t, cnt, basep, rowmeta, hbuf);
    k_gemm2<<<dim3(16, 8, 8), 256, 0, stream>>>(hbuf, w2t, cnt, basep, rowmeta, rowgate, out2);
    k_combine<<<2048, 256, 0, stream>>>(out2, out);
}